// Round 13
// baseline (709.138 us; speedup 1.0000x reference)
//
#include <hip/hip_runtime.h>
#include <stdint.h>

#define HASH_BUCKETS 1000
#define EMB_DIM 16
#define HDIM 32
#define G4 128   // 4*HDIM
#define TSTEPS 512
#define BATCH 4096

typedef short v8s __attribute__((ext_vector_type(8)));   // 8 bf16 (4 VGPRs)
typedef float v4f __attribute__((ext_vector_type(4)));   // MFMA acc

__device__ __forceinline__ float frcp(float x) {
    float r; asm("v_rcp_f32 %0, %1" : "=v"(r) : "v"(x)); return r;
}
__device__ __forceinline__ float fexp2(float x) {
    float r; asm("v_exp_f32 %0, %1" : "=v"(r) : "v"(x)); return r;
}
// f32 -> bf16 (RNE), bits in low 16
__device__ __forceinline__ uint32_t bf16rne(float x) {
    uint32_t u = __float_as_uint(x);
    return (u + 0x7FFFu + ((u >> 16) & 1u)) >> 16;
}

// ---------------------------------------------------------------------------
// Kernel 1: embedding folded through input projection, lane-friendly layout:
// P3[bucket][quad][ci][g] = sum_e emb[bucket][e] * kernel[e][g*32 + 4ci+quad]
// so main-kernel lane (col,quad) reads 8 contiguous float4s per step.
// ---------------------------------------------------------------------------
__global__ void precompute_P3_kernel(const float* __restrict__ emb,
                                     const float* __restrict__ kern,
                                     float* __restrict__ P3) {
    int idx = blockIdx.x * blockDim.x + threadIdx.x;
    if (idx >= HASH_BUCKETS * G4) return;
    int b    = idx >> 7;
    int rem  = idx & 127;
    int quad = rem >> 5;
    int r2   = rem & 31;
    int ci   = r2 >> 2;
    int g    = r2 & 3;
    int kcol = g * 32 + 4 * ci + quad;
    float acc = 0.f;
#pragma unroll
    for (int e = 0; e < EMB_DIM; ++e)
        acc = fmaf(emb[b * EMB_DIM + e], kern[e * G4 + kcol], acc);
    P3[idx] = acc;
}

// ---------------------------------------------------------------------------
// Kernel 2: single-wave MFMA LSTM — NO barriers, no inter-wave coupling.
// Block = 1 wave = 16 batch; grid 256 = 1 wave/CU. The wave computes the full
// z^T [128 gate-rows x 16 batch] as 8 chunks of 16x16x32 bf16 MFMA (x3
// split-bf16, lo*lo dropped). Chunk ci rows m = tt*4+g -> gatecol
// g*32 + 4ci + tt; C/D layout (col=lane&15, row=quad*4+reg) gives lane
// (quad,col) the (i,f,c,o) of h_idx=4ci+quad, batch=col -> 8 independent
// gate chains/lane (ILP buries trans+MFMA latency). h publish->consume is
// wave-internal via the in-order DS pipe (writes of step t precede reads of
// step t+1 in program order). LDS stride 37: both the b32 writes and the
// b128 reads are <=2-way bank-aliased (free).
// ---------------------------------------------------------------------------
__global__ __launch_bounds__(64)
__attribute__((amdgpu_waves_per_eu(1, 1)))
void lstm_head_kernel(const int* __restrict__ ids,
                      const float* __restrict__ P3,   // [1000][4][8][4]
                      const float* __restrict__ R,    // rec_kernel [32][128]
                      const float* __restrict__ w1,   // [32][32]
                      const float* __restrict__ b1,   // [32]
                      const float* __restrict__ w2,   // [32]
                      const float* __restrict__ b2,   // [1]
                      float* __restrict__ out) {
    __shared__ __align__(16) uint32_t hbuf[16][37];  // packed h (hi|lo bf16)
    __shared__ float hfin[16][33];

    const int lane = threadIdx.x;     // 0..63
    const int col  = lane & 15;       // batch within group
    const int quad = lane >> 4;       // 0..3
    const int bb   = blockIdx.x * 16;

    // ---- A fragments: 8 chunks, split bf16 hi/lo ----
    union V8 { uint32_t u[4]; v8s v; };
    V8 Ahi[8], Alo[8];
    {
        int tt = col >> 2, g = col & 3;
#pragma unroll
        for (int ci = 0; ci < 8; ++ci) {
            int gc = g * 32 + 4 * ci + tt;
#pragma unroll
            for (int r = 0; r < 4; ++r) {
                uint32_t hp[2], lp[2];
#pragma unroll
                for (int e = 0; e < 2; ++e) {
                    int k = quad * 8 + 2 * r + e;
                    float x = R[k * G4 + gc];
                    uint32_t hb = bf16rne(x);
                    hp[e] = hb;
                    lp[e] = bf16rne(x - __uint_as_float(hb << 16));
                }
                Ahi[ci].u[r] = hp[0] | (hp[1] << 16);
                Alo[ci].u[r] = lp[0] | (lp[1] << 16);
            }
        }
    }

    // zero h buffer (h0 = 0); single wave -> program order = DS order
    for (int i = lane; i < 16 * 37; i += 64)
        ((uint32_t*)hbuf)[i] = 0u;

    // ---- xz / id pipeline ----
    const int* __restrict__ idrow = ids + (size_t)(bb + col) * TSTEPS;
    int idc = idrow[0];
    float4 xzA[8], xzB[8];
    {
        const float* base = P3 + (size_t)idc * G4 + quad * 32;
#pragma unroll
        for (int ci = 0; ci < 8; ++ci)
            xzA[ci] = *(const float4*)(base + 4 * ci);
    }
    int idn = idrow[1];

    float cst[8], hv[8];
#pragma unroll
    for (int ci = 0; ci < 8; ++ci) cst[ci] = 0.f;

    const float NL2E = -1.4426950408889634f;
    const float PL2E =  2.8853900817779268f;

    auto step = [&](int t, float4* xzc, float4* xzn) {
        // prefetch next xz (contiguous 128B per lane) + next id
        {
            const float* base = P3 + (size_t)idn * G4 + quad * 32;
#pragma unroll
            for (int ci = 0; ci < 8; ++ci)
                xzn[ci] = *(const float4*)(base + 4 * ci);
        }
        idn = idrow[(t + 2 < TSTEPS) ? (t + 2) : (TSTEPS - 1)];

        // B fragment: h k=quad*8..quad*8+7 for batch=col (2 x b128)
        const uint32_t* hrow = &hbuf[col][0] + 8 * quad;
        uint4 dA = *(const uint4*)hrow;
        uint4 dB = *(const uint4*)(hrow + 4);
        V8 Bhi, Blo;
        Bhi.u[0] = __builtin_amdgcn_perm(dA.y, dA.x, 0x07060302u);
        Bhi.u[1] = __builtin_amdgcn_perm(dA.w, dA.z, 0x07060302u);
        Bhi.u[2] = __builtin_amdgcn_perm(dB.y, dB.x, 0x07060302u);
        Bhi.u[3] = __builtin_amdgcn_perm(dB.w, dB.z, 0x07060302u);
        Blo.u[0] = __builtin_amdgcn_perm(dA.y, dA.x, 0x05040100u);
        Blo.u[1] = __builtin_amdgcn_perm(dA.w, dA.z, 0x05040100u);
        Blo.u[2] = __builtin_amdgcn_perm(dB.y, dB.x, 0x05040100u);
        Blo.u[3] = __builtin_amdgcn_perm(dB.w, dB.z, 0x05040100u);

        // 8 independent chunks: MFMA -> gates -> publish
#pragma unroll
        for (int ci = 0; ci < 8; ++ci) {
            v4f xzv = { xzc[ci].x, xzc[ci].y, xzc[ci].z, xzc[ci].w };
            v4f vz  = { 0.f, 0.f, 0.f, 0.f };
            v4f sa = __builtin_amdgcn_mfma_f32_16x16x32_bf16(Alo[ci].v, Bhi.v, vz,  0, 0, 0);
            v4f sb = __builtin_amdgcn_mfma_f32_16x16x32_bf16(Ahi[ci].v, Blo.v, sa,  0, 0, 0);
            v4f sc = __builtin_amdgcn_mfma_f32_16x16x32_bf16(Ahi[ci].v, Bhi.v, xzv, 0, 0, 0);
            v4f z = sc + sb;

            float si = frcp(1.f + fexp2(fminf(31.f, NL2E * z[0])));
            float sf = frcp(1.f + fexp2(fminf(31.f, NL2E * z[1])));
            float tz = fmaf(-2.f, frcp(1.f + fexp2(fminf(31.f, PL2E * z[2]))), 1.f);
            float so = frcp(1.f + fexp2(fminf(31.f, NL2E * z[3])));
            cst[ci] = fmaf(sf, cst[ci], si * tz);
            float tc = fmaf(-2.f, frcp(1.f + fexp2(fminf(31.f, PL2E * cst[ci]))), 1.f);
            hv[ci] = so * tc;

            uint32_t hb = bf16rne(hv[ci]);
            uint32_t pk = (hb << 16) | bf16rne(hv[ci] - __uint_as_float(hb << 16));
            hbuf[col][4 * ci + quad] = pk;   // read next step by this wave only
        }
    };

    for (int t = 0; t < TSTEPS; t += 2) {
        step(t,     xzA, xzB);
        step(t + 1, xzB, xzA);
    }

    // ---- MLP head ----
#pragma unroll
    for (int ci = 0; ci < 8; ++ci)
        hfin[col][4 * ci + quad] = hv[ci];
    __syncthreads();   // single wave: cheap; guarantees LDS ordering

    int u = lane & 31;
    for (int bq = lane >> 5; bq < 16; bq += 2) {
        float y = b1[u];
#pragma unroll
        for (int k = 0; k < HDIM; ++k)
            y = fmaf(hfin[bq][k], w1[k * HDIM + u], y);
        y = fmaxf(y, 0.f);
        float vv = y * w2[u];
#pragma unroll
        for (int off = 16; off >= 1; off >>= 1)
            vv += __shfl_xor(vv, off);   // within each 32-lane half
        if (u == 0) out[bb + bq] = vv + b2[0];
    }
}

extern "C" void kernel_launch(void* const* d_in, const int* in_sizes, int n_in,
                              void* d_out, int out_size, void* d_ws, size_t ws_size,
                              hipStream_t stream) {
    const int*   ids  = (const int*)d_in[0];
    const float* emb  = (const float*)d_in[1];
    const float* kern = (const float*)d_in[2];
    const float* rec  = (const float*)d_in[3];
    const float* w1   = (const float*)d_in[4];
    const float* b1   = (const float*)d_in[5];
    const float* w2   = (const float*)d_in[6];
    const float* b2   = (const float*)d_in[7];
    float* out = (float*)d_out;
    float* P3  = (float*)d_ws;   // 512 KB scratch

    precompute_P3_kernel<<<(HASH_BUCKETS * G4 + 255) / 256, 256, 0, stream>>>(
        emb, kern, P3);
    lstm_head_kernel<<<BATCH / 16, 64, 0, stream>>>(
        ids, P3, rec, w1, b1, w2, b2, out);
}

// Round 14
// 363.741 us; speedup vs baseline: 1.9496x; 1.9496x over previous
//
#include <hip/hip_runtime.h>
#include <stdint.h>

#define HASH_BUCKETS 1000
#define EMB_DIM 16
#define HDIM 32
#define G4 128   // 4*HDIM
#define TSTEPS 512
#define BATCH 4096

typedef short v8s __attribute__((ext_vector_type(8)));   // 8 bf16 (4 VGPRs)
typedef float v4f __attribute__((ext_vector_type(4)));   // MFMA acc

__device__ __forceinline__ float frcp(float x) {
    float r; asm("v_rcp_f32 %0, %1" : "=v"(r) : "v"(x)); return r;
}
__device__ __forceinline__ float fexp2(float x) {
    float r; asm("v_exp_f32 %0, %1" : "=v"(r) : "v"(x)); return r;
}
// f32 -> bf16 (RNE), bits in low 16
__device__ __forceinline__ uint32_t bf16rne(float x) {
    uint32_t u = __float_as_uint(x);
    return (u + 0x7FFFu + ((u >> 16) & 1u)) >> 16;
}

// ---------------------------------------------------------------------------
// Kernel 1: embedding folded through input projection (r12 layout):
// P2[bucket][h][g] = sum_e emb[bucket][e] * kernel[e][g*32 + h]
// ---------------------------------------------------------------------------
__global__ void precompute_P2_kernel(const float* __restrict__ emb,
                                     const float* __restrict__ kern,
                                     float* __restrict__ P2) {
    int idx = blockIdx.x * blockDim.x + threadIdx.x;
    if (idx >= HASH_BUCKETS * G4) return;
    int row = idx >> 7;
    int c2  = idx & 127;
    int h = c2 >> 2;
    int g = c2 & 3;
    float acc = 0.f;
#pragma unroll
    for (int e = 0; e < EMB_DIM; ++e)
        acc = fmaf(emb[row * EMB_DIM + e], kern[e * G4 + g * 32 + h], acc);
    P2[idx] = acc;
}

// ---------------------------------------------------------------------------
// Kernel 2: wave-local MFMA LSTM — zero barriers, zero cross-wave coupling.
// Block = 1 wave = 4 batch; grid 1024 -> 4 waves/CU (1 per SIMD).
// The 4 batch are REPLICATED across the 16 B-columns (col&3 = batch slot);
// column-group cg = col>>2 owns gate-row chunks {2cg, 2cg+1}, so:
//  - each lane runs exactly 2 gate chains (spread, not concentrated),
//  - each (h,batch) pair is produced by exactly one lane,
//  - h exchange is a wave-internal LDS write -> next-step read (in-order DS
//    pipe => no barrier at all).
// MFMA: 8 chunks x 3 split-bf16 (lo*lo dropped), C=0, xz added post-hoc for
// the lane's own 2 chunks only. MFMA compute is 4x-replicated (the price of
// barrier freedom): per-SIMD matrix pipe ~466 cyc/step is the design floor.
// A/B/C/D mappings identical to r13 (HW-verified passing).
// ---------------------------------------------------------------------------
__global__ __launch_bounds__(64)
__attribute__((amdgpu_waves_per_eu(1, 1)))
void lstm_head_kernel(const int* __restrict__ ids,
                      const float* __restrict__ P2,   // [1000][32][4]
                      const float* __restrict__ R,    // rec_kernel [32][128]
                      const float* __restrict__ w1,   // [32][32]
                      const float* __restrict__ b1,   // [32]
                      const float* __restrict__ w2,   // [32]
                      const float* __restrict__ b2,   // [1]
                      float* __restrict__ out) {
    __shared__ __align__(16) uint32_t hbuf[4][36];   // packed h (hi|lo bf16)
    __shared__ float hfin[4][33];

    const int lane = threadIdx.x;     // 0..63
    const int col  = lane & 15;
    const int quad = lane >> 4;       // 0..3
    const int b4   = col & 3;         // batch slot
    const int cg   = col >> 2;        // chunk-group: owns chunks 2cg, 2cg+1
    const int bb   = blockIdx.x * 4;
    const int h0   = 8 * cg + quad;       // hidx of chunk 2cg
    const int h1   = 8 * cg + 4 + quad;   // hidx of chunk 2cg+1

    // ---- A fragments: 8 chunks, split bf16 hi/lo (mapping as r13) ----
    union V8 { uint32_t u[4]; v8s v; };
    V8 Ahi[8], Alo[8];
    {
        int tt = col >> 2, g = col & 3;
#pragma unroll
        for (int ci = 0; ci < 8; ++ci) {
            int gc = g * 32 + 4 * ci + tt;
#pragma unroll
            for (int r = 0; r < 4; ++r) {
                uint32_t hp[2], lp[2];
#pragma unroll
                for (int e = 0; e < 2; ++e) {
                    int k = quad * 8 + 2 * r + e;
                    float x = R[k * G4 + gc];
                    uint32_t hb = bf16rne(x);
                    hp[e] = hb;
                    lp[e] = bf16rne(x - __uint_as_float(hb << 16));
                }
                Ahi[ci].u[r] = hp[0] | (hp[1] << 16);
                Alo[ci].u[r] = lp[0] | (lp[1] << 16);
            }
        }
    }

    // zero h buffer (h0 = 0); single wave + in-order DS => no barrier needed
    for (int i = lane; i < 4 * 36; i += 64)
        ((uint32_t*)hbuf)[i] = 0u;

    // ---- xz/id pipeline, r12-style distance-2 prefetch ----
    const int* __restrict__ idrow = ids + (size_t)(bb + b4) * TSTEPS;
    int ida = idrow[0];
    float4 xz0_c = *(const float4*)(P2 + (size_t)ida * G4 + 4 * h0);
    float4 xz1_c = *(const float4*)(P2 + (size_t)ida * G4 + 4 * h1);
    int idb = idrow[1];
    float4 xz0_n = *(const float4*)(P2 + (size_t)idb * G4 + 4 * h0);
    float4 xz1_n = *(const float4*)(P2 + (size_t)idb * G4 + 4 * h1);
    int id_c = idrow[2];
    int id_n = idrow[3];

    float c0 = 0.f, c1 = 0.f, hv0 = 0.f, hv1 = 0.f;
    const float NL2E = -1.4426950408889634f;
    const float PL2E =  2.8853900817779268f;
    const v4f vzero = {0.f, 0.f, 0.f, 0.f};

    for (int t = 0; t < TSTEPS; ++t) {
        // issue xz[t+2] now (aged ~1 full body before any dependent wait)
        float4 xz0_f = *(const float4*)(P2 + (size_t)id_c * G4 + 4 * h0);
        float4 xz1_f = *(const float4*)(P2 + (size_t)id_c * G4 + 4 * h1);
        int id_f = idrow[(t + 4 < TSTEPS) ? (t + 4) : (TSTEPS - 1)];

        // B fragment: 8 packed dwords of h for batch=b4 (2 x b128)
        const uint32_t* hrow = &hbuf[b4][0] + 8 * quad;
        uint4 dA = *(const uint4*)hrow;
        uint4 dB = *(const uint4*)(hrow + 4);
        V8 Bhi, Blo;
        Bhi.u[0] = __builtin_amdgcn_perm(dA.y, dA.x, 0x07060302u);
        Bhi.u[1] = __builtin_amdgcn_perm(dA.w, dA.z, 0x07060302u);
        Bhi.u[2] = __builtin_amdgcn_perm(dB.y, dB.x, 0x07060302u);
        Bhi.u[3] = __builtin_amdgcn_perm(dB.w, dB.z, 0x07060302u);
        Blo.u[0] = __builtin_amdgcn_perm(dA.y, dA.x, 0x05040100u);
        Blo.u[1] = __builtin_amdgcn_perm(dA.w, dA.z, 0x05040100u);
        Blo.u[2] = __builtin_amdgcn_perm(dB.y, dB.x, 0x05040100u);
        Blo.u[3] = __builtin_amdgcn_perm(dB.w, dB.z, 0x05040100u);

        // 8 chunks x 3-MFMA split chains; keep only my 2 chunks' z
        v4f zsel0 = vzero, zsel1 = vzero;
#pragma unroll
        for (int ci = 0; ci < 8; ++ci) {
            v4f sa = __builtin_amdgcn_mfma_f32_16x16x32_bf16(Alo[ci].v, Bhi.v, vzero, 0, 0, 0);
            v4f sb = __builtin_amdgcn_mfma_f32_16x16x32_bf16(Ahi[ci].v, Blo.v, sa, 0, 0, 0);
            v4f sc = __builtin_amdgcn_mfma_f32_16x16x32_bf16(Ahi[ci].v, Bhi.v, sb, 0, 0, 0);
            if ((ci >> 1) == cg) {
                if ((ci & 1) == 0) zsel0 = sc; else zsel1 = sc;
            }
        }
        v4f z0 = { zsel0[0] + xz0_c.x, zsel0[1] + xz0_c.y,
                   zsel0[2] + xz0_c.z, zsel0[3] + xz0_c.w };
        v4f z1 = { zsel1[0] + xz1_c.x, zsel1[1] + xz1_c.y,
                   zsel1[2] + xz1_c.z, zsel1[3] + xz1_c.w };

        // ---- 2 gate chains per lane ----
        float si0 = frcp(1.f + fexp2(fminf(31.f, NL2E * z0[0])));
        float sf0 = frcp(1.f + fexp2(fminf(31.f, NL2E * z0[1])));
        float tz0 = fmaf(-2.f, frcp(1.f + fexp2(fminf(31.f, PL2E * z0[2]))), 1.f);
        float so0 = frcp(1.f + fexp2(fminf(31.f, NL2E * z0[3])));
        float si1 = frcp(1.f + fexp2(fminf(31.f, NL2E * z1[0])));
        float sf1 = frcp(1.f + fexp2(fminf(31.f, NL2E * z1[1])));
        float tz1 = fmaf(-2.f, frcp(1.f + fexp2(fminf(31.f, PL2E * z1[2]))), 1.f);
        float so1 = frcp(1.f + fexp2(fminf(31.f, NL2E * z1[3])));

        c0 = fmaf(sf0, c0, si0 * tz0);
        c1 = fmaf(sf1, c1, si1 * tz1);
        float tc0 = fmaf(-2.f, frcp(1.f + fexp2(fminf(31.f, PL2E * c0))), 1.f);
        float tc1 = fmaf(-2.f, frcp(1.f + fexp2(fminf(31.f, PL2E * c1))), 1.f);
        hv0 = so0 * tc0;
        hv1 = so1 * tc1;

        // publish h (split-bf16 packed); in-order DS pipe orders these before
        // the next iteration's b128 reads — no barrier, single wave
        uint32_t hb0 = bf16rne(hv0);
        uint32_t pk0 = (hb0 << 16) | bf16rne(hv0 - __uint_as_float(hb0 << 16));
        uint32_t hb1 = bf16rne(hv1);
        uint32_t pk1 = (hb1 << 16) | bf16rne(hv1 - __uint_as_float(hb1 << 16));
        hbuf[b4][h0] = pk0;
        hbuf[b4][h1] = pk1;

        // rotate prefetch pipelines
        xz0_c = xz0_n; xz1_c = xz1_n;
        xz0_n = xz0_f; xz1_n = xz1_f;
        id_c = id_n;
        id_n = id_f;
    }

    // ---- MLP head (4 batch, wave-local) ----
    hfin[b4][h0] = hv0;
    hfin[b4][h1] = hv1;
    __syncthreads();   // single wave: near-free; guarantees LDS ordering

    int u = lane & 31;
    for (int bq = lane >> 5; bq < 4; bq += 2) {
        float y = b1[u];
#pragma unroll
        for (int k = 0; k < HDIM; ++k)
            y = fmaf(hfin[bq][k], w1[k * HDIM + u], y);
        y = fmaxf(y, 0.f);
        float vv = y * w2[u];
#pragma unroll
        for (int off = 16; off >= 1; off >>= 1)
            vv += __shfl_xor(vv, off);   // within each 32-lane half
        if (u == 0) out[bb + bq] = vv + b2[0];
    }
}

extern "C" void kernel_launch(void* const* d_in, const int* in_sizes, int n_in,
                              void* d_out, int out_size, void* d_ws, size_t ws_size,
                              hipStream_t stream) {
    const int*   ids  = (const int*)d_in[0];
    const float* emb  = (const float*)d_in[1];
    const float* kern = (const float*)d_in[2];
    const float* rec  = (const float*)d_in[3];
    const float* w1   = (const float*)d_in[4];
    const float* b1   = (const float*)d_in[5];
    const float* w2   = (const float*)d_in[6];
    const float* b2   = (const float*)d_in[7];
    float* out = (float*)d_out;
    float* P2  = (float*)d_ws;   // 512 KB scratch

    precompute_P2_kernel<<<(HASH_BUCKETS * G4 + 255) / 256, 256, 0, stream>>>(
        emb, kern, P2);
    lstm_head_kernel<<<BATCH / 4, 64, 0, stream>>>(
        ids, P2, rec, w1, b1, w2, b2, out);
}

// Round 15
// 353.213 us; speedup vs baseline: 2.0077x; 1.0298x over previous
//
#include <hip/hip_runtime.h>
#include <stdint.h>

#define HASH_BUCKETS 1000
#define EMB_DIM 16
#define HDIM 32
#define G4 128   // 4*HDIM
#define TSTEPS 512
#define BATCH 4096

typedef short v8s __attribute__((ext_vector_type(8)));   // 8 bf16 (4 VGPRs)
typedef float v4f __attribute__((ext_vector_type(4)));   // MFMA acc

__device__ __forceinline__ float frcp(float x) {
    float r; asm("v_rcp_f32 %0, %1" : "=v"(r) : "v"(x)); return r;
}
__device__ __forceinline__ float fexp2(float x) {
    float r; asm("v_exp_f32 %0, %1" : "=v"(r) : "v"(x)); return r;
}
// f32 -> bf16 (RNE), bits in low 16
__device__ __forceinline__ uint32_t bf16rne(float x) {
    uint32_t u = __float_as_uint(x);
    return (u + 0x7FFFu + ((u >> 16) & 1u)) >> 16;
}

// ---------------------------------------------------------------------------
// Kernel 1: embedding folded through input projection (r12 layout):
// P2[bucket][h][g] = sum_e emb[bucket][e] * kernel[e][g*32 + h]
// ---------------------------------------------------------------------------
__global__ void precompute_P2_kernel(const float* __restrict__ emb,
                                     const float* __restrict__ kern,
                                     float* __restrict__ P2) {
    int idx = blockIdx.x * blockDim.x + threadIdx.x;
    if (idx >= HASH_BUCKETS * G4) return;
    int row = idx >> 7;
    int c2  = idx & 127;
    int h = c2 >> 2;
    int g = c2 & 3;
    float acc = 0.f;
#pragma unroll
    for (int e = 0; e < EMB_DIM; ++e)
        acc = fmaf(emb[row * EMB_DIM + e], kern[e * G4 + g * 32 + h], acc);
    P2[idx] = acc;
}

// ---------------------------------------------------------------------------
// Kernel 2: MFMA LSTM with cross-block wave interleaving.
// Block = 256 thr = 4 waves = 8 batch; grid 512 -> 2 blocks/CU -> each SIMD
// hosts 2 waves from INDEPENDENT blocks (r8-proven: independent co-resident
// waves fill each other's chain/barrier stalls; r12's 1-block/CU could not).
// The 8 batch are replicated across both halves of the 16 B-columns.
// Wave w computes chunks 2w & 2w+1 (rows m=tt*4+g -> gatecol g*32+4ci+tt,
// same HW-verified mapping as r12). Lane (quad,col):
//   col<8  -> owns gate chain (h=8w+quad,   batch=col)   <- chunk-2w acc
//   col>=8 -> owns gate chain (h=8w+4+quad, batch=col-8) <- chunk-2w+1 acc
// Every lane's z arrives in its own acc regs (replication makes the two
// column-halves carry the same batch) -> 1 chain/lane, no cross-lane moves.
// Per-lane xz (1 float4) seeds the C operand of the lane's own chunk chain;
// the other chunk's C is garbage on this lane but consumed only by the other
// col-half, where it is correct. Gates: r8's grouped-reciprocal (7 trans).
// ---------------------------------------------------------------------------
__global__ __launch_bounds__(256)
__attribute__((amdgpu_waves_per_eu(2, 2)))
void lstm_head_kernel(const int* __restrict__ ids,
                      const float* __restrict__ P2,   // [1000][32][4]
                      const float* __restrict__ R,    // rec_kernel [32][128]
                      const float* __restrict__ w1,   // [32][32]
                      const float* __restrict__ b1,   // [32]
                      const float* __restrict__ w2,   // [32]
                      const float* __restrict__ b2,   // [1]
                      float* __restrict__ out) {
    // stride 37: zero dword0-bank collisions for the b128 reads (5*b8+8q
    // distinct mod 32), <=2-way on b32 writes (free).
    __shared__ __align__(16) uint32_t hbuf[2][8][37];
    __shared__ float hfin[8][33];

    const int tid  = threadIdx.x;
    const int w    = tid >> 6;        // wave 0..3
    const int lane = tid & 63;
    const int col  = lane & 15;
    const int quad = lane >> 4;       // 0..3
    const int b8   = col & 7;         // batch slot (replicated halves)
    const int sel  = col >> 3;        // 0 -> chunk 2w, 1 -> chunk 2w+1
    const int bb   = blockIdx.x * 8;
    const int h0   = 8 * w + quad;    // chunk 2w h-index
    const int h1   = h0 + 4;          // chunk 2w+1 h-index
    const int hsel = sel ? h1 : h0;   // my chain's h-index

    // ---- A fragments for chunks 2w (gc0) and 2w+1 (gc1) — as r12 ----
    union V8 { uint32_t u[4]; v8s v; };
    V8 A0hi, A0lo, A1hi, A1lo;
    {
        int tt = col >> 2, g = col & 3;
        int gc0 = g * 32 + 8 * w + tt;
        int gc1 = gc0 + 4;
#pragma unroll
        for (int r = 0; r < 4; ++r) {
            uint32_t h0p[2], l0p[2], h1p[2], l1p[2];
#pragma unroll
            for (int e = 0; e < 2; ++e) {
                int k = quad * 8 + 2 * r + e;
                float x0 = R[k * G4 + gc0];
                uint32_t hb0 = bf16rne(x0);
                h0p[e] = hb0;
                l0p[e] = bf16rne(x0 - __uint_as_float(hb0 << 16));
                float x1 = R[k * G4 + gc1];
                uint32_t hb1 = bf16rne(x1);
                h1p[e] = hb1;
                l1p[e] = bf16rne(x1 - __uint_as_float(hb1 << 16));
            }
            A0hi.u[r] = h0p[0] | (h0p[1] << 16);
            A0lo.u[r] = l0p[0] | (l0p[1] << 16);
            A1hi.u[r] = h1p[0] | (h1p[1] << 16);
            A1lo.u[r] = l1p[0] | (l1p[1] << 16);
        }
    }

    for (int i = tid; i < 2 * 8 * 37; i += 256)
        ((uint32_t*)hbuf)[i] = 0u;

    // ---- per-lane xz/id pipeline (distance-2, r12-proven) ----
    const int* __restrict__ idrow = ids + (size_t)(bb + b8) * TSTEPS;
    int ida = idrow[0];
    float4 xz_c = *(const float4*)(P2 + (size_t)ida * G4 + 4 * hsel);
    int idb = idrow[1];
    float4 xz_n = *(const float4*)(P2 + (size_t)idb * G4 + 4 * hsel);
    int id_c = idrow[2];
    int id_n = idrow[3];

    float cst = 0.f, hv = 0.f;
    int p = 0;
    const float NL2E = -1.4426950408889634f;
    const float PL2E =  2.8853900817779268f;
    const v4f vzero = {0.f, 0.f, 0.f, 0.f};

    __syncthreads();

    for (int t = 0; t < TSTEPS; ++t) {
        // issue xz[t+2] now (aged ~1 full body before the barrier drain)
        float4 xz_f = *(const float4*)(P2 + (size_t)id_c * G4 + 4 * hsel);
        int id_f = idrow[(t + 4 < TSTEPS) ? (t + 4) : (TSTEPS - 1)];

        // B fragment: 8 packed dwords of h for batch=b8 (2 x b128)
        const uint32_t* hrow = &hbuf[p][b8][0] + 8 * quad;
        uint4 dA = *(const uint4*)hrow;
        uint4 dB = *(const uint4*)(hrow + 4);
        V8 Bhi, Blo;
        Bhi.u[0] = __builtin_amdgcn_perm(dA.y, dA.x, 0x07060302u);
        Bhi.u[1] = __builtin_amdgcn_perm(dA.w, dA.z, 0x07060302u);
        Bhi.u[2] = __builtin_amdgcn_perm(dB.y, dB.x, 0x07060302u);
        Bhi.u[3] = __builtin_amdgcn_perm(dB.w, dB.z, 0x07060302u);
        Blo.u[0] = __builtin_amdgcn_perm(dA.y, dA.x, 0x05040100u);
        Blo.u[1] = __builtin_amdgcn_perm(dA.w, dA.z, 0x05040100u);
        Blo.u[2] = __builtin_amdgcn_perm(dB.y, dB.x, 0x05040100u);
        Blo.u[3] = __builtin_amdgcn_perm(dB.w, dB.z, 0x05040100u);

        // z = Ahi*Bhi + Ahi*Blo + Alo*Bhi + xz  (lo*lo dropped)
        // xzv seeds BOTH chunk chains; each col-half consumes the chunk
        // where its C was valid.
        v4f xzv = { xz_c.x, xz_c.y, xz_c.z, xz_c.w };
        v4f s0a = __builtin_amdgcn_mfma_f32_16x16x32_bf16(A0lo.v, Bhi.v, vzero, 0, 0, 0);
        v4f s1a = __builtin_amdgcn_mfma_f32_16x16x32_bf16(A1lo.v, Bhi.v, vzero, 0, 0, 0);
        v4f s0b = __builtin_amdgcn_mfma_f32_16x16x32_bf16(A0hi.v, Blo.v, s0a, 0, 0, 0);
        v4f s1b = __builtin_amdgcn_mfma_f32_16x16x32_bf16(A1hi.v, Blo.v, s1a, 0, 0, 0);
        v4f s0c = __builtin_amdgcn_mfma_f32_16x16x32_bf16(A0hi.v, Bhi.v, xzv, 0, 0, 0);
        v4f s1c = __builtin_amdgcn_mfma_f32_16x16x32_bf16(A1hi.v, Bhi.v, xzv, 0, 0, 0);
        v4f z0v = s0c + s0b;
        v4f z1v = s1c + s1b;

        float zi = sel ? z1v[0] : z0v[0];
        float zf = sel ? z1v[1] : z0v[1];
        float zc = sel ? z1v[2] : z0v[2];
        float zo = sel ? z1v[3] : z0v[3];

        // ---- grouped-reciprocal gates (r8 math; 5 exp + 2 rcp) ----
        float di = 1.f + fexp2(fminf(31.f, NL2E * zi));
        float df = 1.f + fexp2(fminf(31.f, NL2E * zf));
        float dc = 1.f + fexp2(fminf(31.f, PL2E * zc));
        float dq = 1.f + fexp2(fminf(31.f, NL2E * zo));
        float Pp = di * df;
        float Qq = dc * dq;
        float rr = frcp(Pp * Qq);
        float rP = rr * Qq;              // 1/(di*df)
        float rQ = rr * Pp;              // 1/(dc*dq)
        float ig = rP * df;              // sigmoid(zi)
        float fg = rP * di;              // sigmoid(zf)
        float rc = rQ * dq;              // 1/dc
        float og = rQ * dc;              // sigmoid(zo)
        float tz = fmaf(-2.f, rc, 1.f);  // tanh(zc)
        cst = fmaf(fg, cst, ig * tz);
        float tc = fmaf(-2.f, frcp(1.f + fexp2(fminf(31.f, PL2E * cst))), 1.f);
        hv = og * tc;

        // publish h (split-bf16 packed)
        uint32_t hb = bf16rne(hv);
        uint32_t pk = (hb << 16) | bf16rne(hv - __uint_as_float(hb << 16));
        hbuf[p ^ 1][b8][hsel] = pk;

        // rotate prefetch pipelines
        xz_c = xz_n;
        xz_n = xz_f;
        id_c = id_n;
        id_n = id_f;

        __syncthreads();
        p ^= 1;
    }

    // ---- MLP head (8 batch per block) ----
    hfin[b8][hsel] = hv;
    __syncthreads();

    int u  = tid & 31;
    int bq = tid >> 5;   // 0..7
    float y = b1[u];
#pragma unroll
    for (int k = 0; k < HDIM; ++k)
        y = fmaf(hfin[bq][k], w1[k * HDIM + u], y);
    y = fmaxf(y, 0.f);
    float vv = y * w2[u];
#pragma unroll
    for (int off = 16; off >= 1; off >>= 1)
        vv += __shfl_xor(vv, off);   // within each 32-lane group
    if (u == 0) out[bb + bq] = vv + b2[0];
}

extern "C" void kernel_launch(void* const* d_in, const int* in_sizes, int n_in,
                              void* d_out, int out_size, void* d_ws, size_t ws_size,
                              hipStream_t stream) {
    const int*   ids  = (const int*)d_in[0];
    const float* emb  = (const float*)d_in[1];
    const float* kern = (const float*)d_in[2];
    const float* rec  = (const float*)d_in[3];
    const float* w1   = (const float*)d_in[4];
    const float* b1   = (const float*)d_in[5];
    const float* w2   = (const float*)d_in[6];
    const float* b2   = (const float*)d_in[7];
    float* out = (float*)d_out;
    float* P2  = (float*)d_ws;   // 512 KB scratch

    precompute_P2_kernel<<<(HASH_BUCKETS * G4 + 255) / 256, 256, 0, stream>>>(
        emb, kern, P2);
    lstm_head_kernel<<<BATCH / 8, 256, 0, stream>>>(
        ids, P2, rec, w1, b1, w2, b2, out);
}

// Round 16
// 321.963 us; speedup vs baseline: 2.2025x; 1.0971x over previous
//
#include <hip/hip_runtime.h>
#include <stdint.h>

#define HASH_BUCKETS 1000
#define EMB_DIM 16
#define HDIM 32
#define G4 128   // 4*HDIM
#define TSTEPS 512
#define BATCH 4096

typedef short v8s __attribute__((ext_vector_type(8)));   // 8 bf16 (4 VGPRs)
typedef float v4f __attribute__((ext_vector_type(4)));   // MFMA acc

__device__ __forceinline__ float frcp(float x) {
    float r; asm("v_rcp_f32 %0, %1" : "=v"(r) : "v"(x)); return r;
}
__device__ __forceinline__ float fexp2(float x) {
    float r; asm("v_exp_f32 %0, %1" : "=v"(r) : "v"(x)); return r;
}
// f32 -> bf16 (RNE), bits in low 16
__device__ __forceinline__ uint32_t bf16rne(float x) {
    uint32_t u = __float_as_uint(x);
    return (u + 0x7FFFu + ((u >> 16) & 1u)) >> 16;
}

// ---------------------------------------------------------------------------
// Kernel 1: embedding folded through input projection (r12 layout):
// P2[bucket][h][g] = sum_e emb[bucket][e] * kernel[e][g*32 + h]
// ---------------------------------------------------------------------------
__global__ void precompute_P2_kernel(const float* __restrict__ emb,
                                     const float* __restrict__ kern,
                                     float* __restrict__ P2) {
    int idx = blockIdx.x * blockDim.x + threadIdx.x;
    if (idx >= HASH_BUCKETS * G4) return;
    int row = idx >> 7;
    int c2  = idx & 127;
    int h = c2 >> 2;
    int g = c2 & 3;
    float acc = 0.f;
#pragma unroll
    for (int e = 0; e < EMB_DIM; ++e)
        acc = fmaf(emb[row * EMB_DIM + e], kern[e * G4 + g * 32 + h], acc);
    P2[idx] = acc;
}

// ---------------------------------------------------------------------------
// Kernel 2: r12 champion structure (block = 4 waves = 16 batch, grid 256,
// distance-2 xz prefetch) with two critical-path trims:
//  (a) grouped-reciprocal gates (r8/r15-verified): 7 trans/chain instead of
//      10 — trans issue slots (16 cyc each, quarter rate) serialize between
//      the 2 ILP chains, so this cuts ~96 cyc/step of quasi-chain occupancy;
//  (b) XOR bank swizzle of the h buffer: slot = 8*((h>>3)^(col&3)) + (h&7).
//      Logical k-order per reader lane is unchanged (reader base
//      8*(quad^(col&3)), still 32B-aligned b128), but read base banks drop
//      from 8-way to <=2-way aliasing (r12 measured 6.3e6 conflicts, the
//      B-read sits ON the serial chain).
// ---------------------------------------------------------------------------
__global__ __launch_bounds__(256)
__attribute__((amdgpu_waves_per_eu(1, 1)))
void lstm_head_kernel(const int* __restrict__ ids,
                      const float* __restrict__ P2,   // [1000][32][4]
                      const float* __restrict__ R,    // rec_kernel [32][128]
                      const float* __restrict__ w1,   // [32][32]
                      const float* __restrict__ b1,   // [32]
                      const float* __restrict__ w2,   // [32]
                      const float* __restrict__ b2,   // [1]
                      float* __restrict__ out) {
    __shared__ __align__(16) uint32_t hbuf[2][16][36];
    __shared__ float hfin[16][33];

    const int tid  = threadIdx.x;
    const int w    = tid >> 6;        // wave 0..3
    const int lane = tid & 63;
    const int col  = lane & 15;       // batch within group
    const int quad = lane >> 4;       // 0..3
    const int bb   = blockIdx.x * 16;
    const int h0   = 8 * w + quad;
    const int h1   = h0 + 4;
    const int sw   = col & 3;         // bank swizzle key

    // ---- A fragments for chunks 2w (gc0) and 2w+1 (gc1) ----
    union V8 { uint32_t u[4]; v8s v; };
    V8 A0hi, A0lo, A1hi, A1lo;
    {
        int tt = col >> 2, g = col & 3;
        int gc0 = g * 32 + 8 * w + tt;
        int gc1 = gc0 + 4;
#pragma unroll
        for (int r = 0; r < 4; ++r) {
            uint32_t h0p[2], l0p[2], h1p[2], l1p[2];
#pragma unroll
            for (int e = 0; e < 2; ++e) {
                int k = quad * 8 + 2 * r + e;
                float x0 = R[k * G4 + gc0];
                uint32_t hb0 = bf16rne(x0);
                h0p[e] = hb0;
                l0p[e] = bf16rne(x0 - __uint_as_float(hb0 << 16));
                float x1 = R[k * G4 + gc1];
                uint32_t hb1 = bf16rne(x1);
                h1p[e] = hb1;
                l1p[e] = bf16rne(x1 - __uint_as_float(hb1 << 16));
            }
            A0hi.u[r] = h0p[0] | (h0p[1] << 16);
            A0lo.u[r] = l0p[0] | (l0p[1] << 16);
            A1hi.u[r] = h1p[0] | (h1p[1] << 16);
            A1lo.u[r] = l1p[0] | (l1p[1] << 16);
        }
    }

    for (int i = tid; i < 2 * 16 * 36; i += 256)
        ((uint32_t*)hbuf)[i] = 0u;

    // ---- deep prefetch pipeline (distance 2, r12-proven) ----
    const int* __restrict__ idrow = ids + (size_t)(bb + col) * TSTEPS;
    int ida = idrow[0];
    float4 xz0_c = *(const float4*)(P2 + (size_t)ida * G4 + 4 * h0);
    float4 xz1_c = *(const float4*)(P2 + (size_t)ida * G4 + 4 * h1);
    int idb = idrow[1];
    float4 xz0_n = *(const float4*)(P2 + (size_t)idb * G4 + 4 * h0);
    float4 xz1_n = *(const float4*)(P2 + (size_t)idb * G4 + 4 * h1);
    int id_c = idrow[2];
    int id_n = idrow[3];

    float c0 = 0.f, c1 = 0.f, hv0 = 0.f, hv1 = 0.f;
    int p = 0;
    const float NL2E = -1.4426950408889634f;
    const float PL2E =  2.8853900817779268f;
    const v4f vzero = {0.f, 0.f, 0.f, 0.f};

    __syncthreads();

    for (int t = 0; t < TSTEPS; ++t) {
        // issue xz[t+2] now (aged ~1 full body before the barrier drain)
        float4 xz0_f = *(const float4*)(P2 + (size_t)id_c * G4 + 4 * h0);
        float4 xz1_f = *(const float4*)(P2 + (size_t)id_c * G4 + 4 * h1);
        int id_f = idrow[(t + 4 < TSTEPS) ? (t + 4) : (TSTEPS - 1)];

        // B fragment: swizzled 8-dword group (logical k = quad*8 + e)
        const uint32_t* hrow = &hbuf[p][col][0] + 8 * (quad ^ sw);
        uint4 dA = *(const uint4*)hrow;
        uint4 dB = *(const uint4*)(hrow + 4);

        V8 Bhi, Blo;
        Bhi.u[0] = __builtin_amdgcn_perm(dA.y, dA.x, 0x07060302u);
        Bhi.u[1] = __builtin_amdgcn_perm(dA.w, dA.z, 0x07060302u);
        Bhi.u[2] = __builtin_amdgcn_perm(dB.y, dB.x, 0x07060302u);
        Bhi.u[3] = __builtin_amdgcn_perm(dB.w, dB.z, 0x07060302u);
        Blo.u[0] = __builtin_amdgcn_perm(dA.y, dA.x, 0x05040100u);
        Blo.u[1] = __builtin_amdgcn_perm(dA.w, dA.z, 0x05040100u);
        Blo.u[2] = __builtin_amdgcn_perm(dB.y, dB.x, 0x05040100u);
        Blo.u[3] = __builtin_amdgcn_perm(dB.w, dB.z, 0x05040100u);

        // z = Ahi*Bhi + Ahi*Blo + Alo*Bhi + xz  (lo*lo dropped)
        v4f s0a = __builtin_amdgcn_mfma_f32_16x16x32_bf16(A0lo.v, Bhi.v, vzero, 0, 0, 0);
        v4f s1a = __builtin_amdgcn_mfma_f32_16x16x32_bf16(A1lo.v, Bhi.v, vzero, 0, 0, 0);
        v4f s0b = __builtin_amdgcn_mfma_f32_16x16x32_bf16(A0hi.v, Blo.v, s0a, 0, 0, 0);
        v4f s1b = __builtin_amdgcn_mfma_f32_16x16x32_bf16(A1hi.v, Blo.v, s1a, 0, 0, 0);
        v4f xzv0 = {xz0_c.x, xz0_c.y, xz0_c.z, xz0_c.w};
        v4f xzv1 = {xz1_c.x, xz1_c.y, xz1_c.z, xz1_c.w};
        v4f s0c = __builtin_amdgcn_mfma_f32_16x16x32_bf16(A0hi.v, Bhi.v, xzv0, 0, 0, 0);
        v4f s1c = __builtin_amdgcn_mfma_f32_16x16x32_bf16(A1hi.v, Bhi.v, xzv1, 0, 0, 0);
        v4f z0 = s0c + s0b;
        v4f z1 = s1c + s1b;

        // ---- grouped-reciprocal gates, 2 chains (5 exp + 2 rcp each) ----
        float di0 = 1.f + fexp2(fminf(31.f, NL2E * z0[0]));
        float df0 = 1.f + fexp2(fminf(31.f, NL2E * z0[1]));
        float dc0 = 1.f + fexp2(fminf(31.f, PL2E * z0[2]));
        float dq0 = 1.f + fexp2(fminf(31.f, NL2E * z0[3]));
        float di1 = 1.f + fexp2(fminf(31.f, NL2E * z1[0]));
        float df1 = 1.f + fexp2(fminf(31.f, NL2E * z1[1]));
        float dc1 = 1.f + fexp2(fminf(31.f, PL2E * z1[2]));
        float dq1 = 1.f + fexp2(fminf(31.f, NL2E * z1[3]));

        float Pp0 = di0 * df0, Qq0 = dc0 * dq0;
        float Pp1 = di1 * df1, Qq1 = dc1 * dq1;
        float rr0 = frcp(Pp0 * Qq0);
        float rr1 = frcp(Pp1 * Qq1);
        float rP0 = rr0 * Qq0, rQ0 = rr0 * Pp0;
        float rP1 = rr1 * Qq1, rQ1 = rr1 * Pp1;
        float ig0 = rP0 * df0, fg0 = rP0 * di0, rc0 = rQ0 * dq0, og0 = rQ0 * dc0;
        float ig1 = rP1 * df1, fg1 = rP1 * di1, rc1 = rQ1 * dq1, og1 = rQ1 * dc1;
        float tz0 = fmaf(-2.f, rc0, 1.f);
        float tz1 = fmaf(-2.f, rc1, 1.f);

        c0 = fmaf(fg0, c0, ig0 * tz0);
        c1 = fmaf(fg1, c1, ig1 * tz1);
        float tc0 = fmaf(-2.f, frcp(1.f + fexp2(fminf(31.f, PL2E * c0))), 1.f);
        float tc1 = fmaf(-2.f, frcp(1.f + fexp2(fminf(31.f, PL2E * c1))), 1.f);
        hv0 = og0 * tc0;
        hv1 = og1 * tc1;

        // publish h (split-bf16 packed), swizzled slot:
        // h0 = 8w+quad  -> 8*(w^sw) + quad ; h1 = 8w+4+quad -> 8*(w^sw)+4+quad
        uint32_t hb0 = bf16rne(hv0);
        uint32_t pk0 = (hb0 << 16) | bf16rne(hv0 - __uint_as_float(hb0 << 16));
        uint32_t hb1 = bf16rne(hv1);
        uint32_t pk1 = (hb1 << 16) | bf16rne(hv1 - __uint_as_float(hb1 << 16));
        int slotbase = 8 * (w ^ sw);
        hbuf[p ^ 1][col][slotbase + quad]     = pk0;
        hbuf[p ^ 1][col][slotbase + 4 + quad] = pk1;

        // rotate pipelines
        xz0_c = xz0_n; xz1_c = xz1_n;
        xz0_n = xz0_f; xz1_n = xz1_f;
        id_c = id_n;
        id_n = id_f;

        __syncthreads();
        p ^= 1;
    }

    // ---- MLP head ----
    hfin[col][h0] = hv0;
    hfin[col][h1] = hv1;
    __syncthreads();

    int u = tid & 31;
    for (int bq = tid >> 5; bq < 16; bq += 8) {
        float y = b1[u];
#pragma unroll
        for (int k = 0; k < HDIM; ++k)
            y = fmaf(hfin[bq][k], w1[k * HDIM + u], y);
        y = fmaxf(y, 0.f);
        float vv = y * w2[u];
#pragma unroll
        for (int off = 16; off >= 1; off >>= 1)
            vv += __shfl_xor(vv, off);
        if (u == 0) out[bb + bq] = vv + b2[0];
    }
}

extern "C" void kernel_launch(void* const* d_in, const int* in_sizes, int n_in,
                              void* d_out, int out_size, void* d_ws, size_t ws_size,
                              hipStream_t stream) {
    const int*   ids  = (const int*)d_in[0];
    const float* emb  = (const float*)d_in[1];
    const float* kern = (const float*)d_in[2];
    const float* rec  = (const float*)d_in[3];
    const float* w1   = (const float*)d_in[4];
    const float* b1   = (const float*)d_in[5];
    const float* w2   = (const float*)d_in[6];
    const float* b2   = (const float*)d_in[7];
    float* out = (float*)d_out;
    float* P2  = (float*)d_ws;   // 512 KB scratch

    precompute_P2_kernel<<<(HASH_BUCKETS * G4 + 255) / 256, 256, 0, stream>>>(
        emb, kern, P2);
    lstm_head_kernel<<<BATCH / 16, 256, 0, stream>>>(
        ids, P2, rec, w1, b1, w2, b2, out);
}